// Round 15
// baseline (246.479 us; speedup 1.0000x reference)
//
#include <hip/hip_runtime.h>
#include <hip/hip_bf16.h>

#define NB_OBJ   5
#define DIM_BODY 10
#define DIM_OBJ  15
#define N_PERM   20
#define HID      256
#define DMP      128
#define ACT      4
#define BATCH    32768
#define GOAL_DIM 30
#define DIN      19
#define OBS_LEN  85
#define TB       4                 // batch elements per block
#define MROWS    80                // TB * N_PERM, 5 M-tiles

typedef __hip_bfloat16 bf16;
typedef __attribute__((ext_vector_type(8))) short s16x8;
typedef __attribute__((ext_vector_type(4))) float f32x4;
typedef __attribute__((ext_vector_type(2))) unsigned u32x2;

#define MFMA16(a, b, c) __builtin_amdgcn_mfma_f32_16x16x32_bf16((a), (b), (c), 0, 0, 0)

// ---- packed-weight offsets in d_ws (bf16 element units) ----
// tiled: [nt][kt][c(4)][n16(16)][j(8)] = W[kt*32+c*8+j][nt*16+n16]
#define OFF_W1   0          // NT=16, KT=1 -> 8192 (k=19 row = b1 bias fold)
#define OFF_W2   8192       // NT=8,  KT=8 -> 32768
#define OFF_M    40960      // NT=8,  KT=4 -> 16384   M = Wq Wk^T / sqrt(128)
#define OFF_WVR  57344      // NT=16, KT=4 -> 32768   Wvr = Wv @ Wr (no relu between)
#define OFF_WP   90112      // 128 f32 (w' = Wk bq / sqrt(128)) -> 256 slots
#define OFF_BVR  90368      // 256 f32 (bvr = 20*bv@Wr + br) -> 512 slots
#define OFF_WH   90880      // head weights [Wm|Ws] as A-frag tiles, KT=8 -> 4096
#define OFF_TBL  94976      // gather table tbl[20][32] int16 -> 640 slots
#define PACK_TOTAL 95232

// fast f32->bf16, round-half-up; tie-behavior-only delta vs RNE
__device__ __forceinline__ unsigned short bfr(float x) {
    return (unsigned short)((__float_as_uint(x) + 0x8000u) >> 16);
}
__device__ __forceinline__ unsigned pkbf(float a, float b) {
    return ((__float_as_uint(a) + 0x8000u) >> 16)
         | ((__float_as_uint(b) + 0x8000u) & 0xffff0000u);
}

// ---- XOR-swizzled layout (kept for t only) ----
__device__ __forceinline__ s16x8 frag_lds(const bf16* base, int m, int stride, int kof, int bprm) {
    int phys = (((kof >> 3) ^ (m & bprm)) << 3);
    return *(const s16x8*)(base + m * stride + phys);
}
__device__ __forceinline__ void store_c4(bf16* base, int m, int stride, int n0,
                                         int bprm, f32x4 acc, f32x4 bs, bool do_relu) {
    float v0 = acc[0] + bs[0], v1 = acc[1] + bs[1];
    float v2 = acc[2] + bs[2], v3 = acc[3] + bs[3];
    if (do_relu) {
        v0 = fmaxf(v0, 0.f); v1 = fmaxf(v1, 0.f);
        v2 = fmaxf(v2, 0.f); v3 = fmaxf(v3, 0.f);
    }
    u32x2 w;
    w.x = pkbf(v0, v1);
    w.y = pkbf(v2, v3);
    int blk = ((n0 >> 3) ^ (m & bprm));
    *(u32x2*)(base + m * stride + blk * 8 + (n0 & 7)) = w;
}

// ---- affine k-block layout: elem (m,k) at [(k>>3)][m][k&7] ----
// addresses affine in unrolled kt/mt -> compiler folds into ds offset imm
__device__ __forceinline__ s16x8 frag_aff(const bf16* base, int rows, int m, int kof) {
    return *(const s16x8*)(base + ((kof >> 3) * rows + m) * 8);
}
__device__ __forceinline__ void store_aff4(bf16* base, int rows, int m, int n0,
                                           f32x4 acc, f32x4 bs, bool do_relu) {
    float v0 = acc[0] + bs[0], v1 = acc[1] + bs[1];
    float v2 = acc[2] + bs[2], v3 = acc[3] + bs[3];
    if (do_relu) {
        v0 = fmaxf(v0, 0.f); v1 = fmaxf(v1, 0.f);
        v2 = fmaxf(v2, 0.f); v3 = fmaxf(v3, 0.f);
    }
    u32x2 w;
    w.x = pkbf(v0, v1);
    w.y = pkbf(v2, v3);
    *(u32x2*)(base + ((n0 >> 3) * rows + m) * 8 + (n0 & 7)) = w;
}

// ================= prepack (identical to R14) =================
__device__ __forceinline__ void pack_tiled(const float* __restrict__ W, int Kact, int N,
                                           int KT, bf16* __restrict__ dst, int idx) {
    int tile = idx >> 9;
    int r    = idx & 511;
    int kt   = tile % KT, nt = tile / KT;
    int c    = r >> 7;
    int rem  = r & 127;
    int n16  = rem >> 3, j = rem & 7;
    int k    = kt * 32 + c * 8 + j;
    float v  = (k < Kact) ? W[k * N + nt * 16 + n16] : 0.f;
    dst[idx] = __float2bfloat16(v);
}

__global__ __launch_bounds__(256) void prepack_kernel(
    const float* __restrict__ W1, const float* __restrict__ b1,
    const float* __restrict__ W2,
    const float* __restrict__ Wq, const float* __restrict__ bq,
    const float* __restrict__ Wk,
    const float* __restrict__ Wv, const float* __restrict__ bv,
    const float* __restrict__ Wr, const float* __restrict__ br,
    const float* __restrict__ Wm, const float* __restrict__ Wsc,
    const int* __restrict__ edges, const int* __restrict__ pred_ids,
    bf16* __restrict__ ws) {
    const float scl = 0.08838834764831845f;   // 1/sqrt(128)
    int idx = blockIdx.x * 256 + threadIdx.x;
    if (idx < 8192) {               // W1 with bias folded into k=19
        int nt = idx >> 9, r = idx & 511;
        int c = r >> 7, rem = r & 127, n16 = rem >> 3, j = rem & 7;
        int k = c * 8 + j, n = nt * 16 + n16;
        float v = (k < DIN) ? W1[k * HID + n] : (k == DIN ? b1[n] : 0.f);
        ws[OFF_W1 + idx] = __float2bfloat16(v);
    }
    else if (idx < 40960) pack_tiled(W2, 256, 128, 8, ws + OFF_W2, idx - 8192);
    else if (idx < 57344) {         // M = Wq Wk^T * scl, fragment-tiled, float4 dot
        int i2 = idx - 40960;
        int tile = i2 >> 9, r = i2 & 511;
        int kt = tile & 3, nt = tile >> 2;
        int c = r >> 7, rem = r & 127, n16 = rem >> 3, j = rem & 7;
        int d = kt * 32 + c * 8 + j;
        int e = nt * 16 + n16;
        const float4* qr = (const float4*)(Wq + d * DMP);
        const float4* kr = (const float4*)(Wk + e * DMP);
        float s = 0.f;
        #pragma unroll 8
        for (int t = 0; t < 32; ++t) {
            float4 a = qr[t], b = kr[t];
            s += a.x * b.x + a.y * b.y + a.z * b.z + a.w * b.w;
        }
        ws[OFF_M + i2] = __float2bfloat16(s * scl);
    }
    else if (idx < 90112) {         // WVR = Wv @ Wr (K=128, N=256, KT=4)
        int i2 = idx - 57344;
        int tile = i2 >> 9, r = i2 & 511;
        int kt = tile & 3, nt = tile >> 2;
        int c = r >> 7, rem = r & 127, n16 = rem >> 3, j = rem & 7;
        int k = kt * 32 + c * 8 + j;
        int n = nt * 16 + n16;
        const float* vr = Wv + k * DMP;
        float s = 0.f;
        #pragma unroll 8
        for (int j2 = 0; j2 < DMP; ++j2) s += vr[j2] * Wr[j2 * HID + n];
        ws[OFF_WVR + i2] = __float2bfloat16(s);
    }
    else if (idx < 90240) {         // w'[d] = scl * (Wk row d . bq)
        int d = idx - 90112;
        const float4* kr = (const float4*)(Wk + d * DMP);
        const float4* bq4 = (const float4*)bq;
        float s = 0.f;
        #pragma unroll 8
        for (int t = 0; t < 32; ++t) {
            float4 a = kr[t], b = bq4[t];
            s += a.x * b.x + a.y * b.y + a.z * b.z + a.w * b.w;
        }
        ((float*)(ws + OFF_WP))[d] = s * scl;
    }
    else if (idx < 90496) {         // bvr[n] = 20 * (bv . Wr[:,n]) + br[n]
        int n = idx - 90240;
        float s = 0.f;
        #pragma unroll 8
        for (int j2 = 0; j2 < DMP; ++j2) s += bv[j2] * Wr[j2 * HID + n];
        ((float*)(ws + OFF_BVR))[n] = 20.f * s + br[n];
    }
    else if (idx < 94592) {         // WH: [Wm|Ws] packed as A-frag tiles
        int i2 = idx - 90496;
        int kt = i2 >> 9, r = i2 & 511;
        int c = r >> 7, rem = r & 127, o = rem >> 3, j = rem & 7;
        int k = kt * 32 + c * 8 + j;
        float v = (o < ACT) ? Wm[k * ACT + o]
                : (o < 2 * ACT) ? Wsc[k * ACT + (o - ACT)] : 0.f;
        ws[OFF_WH + i2] = __float2bfloat16(v);
    }
    else if (idx < PACK_TOTAL) {    // gather table
        int i2 = idx - 94592;
        int p = i2 >> 5, c = i2 & 31;
        short t;
        if      (c < 10) t = (short)c;
        else if (c < 13) t = (short)(OBS_LEN + pred_ids[p * 3 + (c - 10)]);
        else if (c < 16) t = (short)(DIM_BODY + edges[p * 2 + 0] * DIM_OBJ + (c - 13));
        else if (c < 19) t = (short)(DIM_BODY + edges[p * 2 + 1] * DIM_OBJ + (c - 16));
        else if (c == 19) t = 115;
        else              t = 116;
        ((short*)(ws + OFF_TBL))[i2] = t;
    }
}

// ================= main fused kernel =================
// LDS: rA 10,816 + rB 20,480 + rC 21,504 = 52,800 B -> 3 blocks/CU (158,400<=163,840)
__global__ __launch_bounds__(256, 3) void actor_main(
    const float* __restrict__ obs, const float* __restrict__ ag, const float* __restrict__ g,
    const float* __restrict__ b2v,
    const float* __restrict__ bm, const float* __restrict__ bsv,
    const bf16* __restrict__ wp, float* __restrict__ out)
{
    const int b0   = blockIdx.x * TB;
    const int tid  = threadIdx.x;
    const int lane = tid & 63;
    const int wav  = tid >> 6;
    const int l15  = lane & 15;
    const int lq   = lane >> 4;

    __shared__ __align__(16) union {              // 10,816 B
        struct {
            float flat[TB][120];                  // [0..84]=obs [85..114]=dg [115]=1 [116..]=0
            short tbl[N_PERM * 32];
            bf16  inp[MROWS][40];                 // K pad 19->32 (+bias col via tbl)
        } a;                                      // 9,600 (dead after xfr loads)
        struct {
            float sc[TB][N_PERM][N_PERM];         // 6,400
            float cs[TB][N_PERM];                 // 320
            bf16  y[16][16][8];                   // 4,096 affine k-block (rows TB..15 stale, masked)
        } p;                                      // 10,816
    } rA;
    __shared__ __align__(16) union {              // 20,480 B
        bf16 hall[16][80][8];                     // affine: one 128-col half of MLP1 out
        bf16 t[MROWS][DMP];                       // XOR layout (stage-5 padded-row reads)
    } rB;
    __shared__ __align__(16) union {              // 21,504 B
        bf16 x[16][84][8];                        // affine (84 rows: stage-5 k1 clamp target)
        bf16 hr[32][16][8];                       // 8,192 affine
    } rC;

    const f32x4 zf = {0.f, 0.f, 0.f, 0.f};
    bf16* hallp = &rB.hall[0][0][0];
    bf16* xp    = &rC.x[0][0][0];
    bf16* yp    = &rA.p.y[0][0][0];
    bf16* hrp   = &rC.hr[0][0][0];

    // ---- stage 0: flat input vector + gather table -> LDS ----
    for (int i = tid; i < TB * 120; i += 256) {
        int bi = i / 120, c = i - bi * 120;
        float v = 0.f;
        if      (c < OBS_LEN) v = obs[(b0 + bi) * OBS_LEN + c];
        else if (c < 115)     v = g[(b0 + bi) * GOAL_DIM + (c - OBS_LEN)]
                                - ag[(b0 + bi) * GOAL_DIM + (c - OBS_LEN)];
        else if (c == 115)    v = 1.0f;
        rA.a.flat[bi][c] = v;
    }
    for (int i = tid; i < N_PERM * 32; i += 256)
        ((short*)rA.a.tbl)[i] = ((const short*)(wp + OFF_TBL))[i];
    __syncthreads();

    // ---- stage 1: build 80 x 32 edge inputs via gather table ----
    for (int idx = tid; idx < MROWS * 32; idx += 256) {
        int m = idx >> 5, c = idx & 31;
        int bi = m / N_PERM, p = m - bi * N_PERM;
        float v = rA.a.flat[bi][rA.a.tbl[p * 32 + c]];
        *(unsigned short*)&rA.a.inp[m][c] = bfr(v);
    }
    __syncthreads();

    // MLP1 input fragments (live across both phases)
    s16x8 xfr[5];
    #pragma unroll
    for (int mt = 0; mt < 5; ++mt)
        xfr[mt] = *(const s16x8*)(&rA.a.inp[mt * 16 + l15][lq * 8]);

    // MLP2 accumulators (live across both phases)
    f32x4 m2a[5], m2b[5];
    #pragma unroll
    for (int mt = 0; mt < 5; ++mt) { m2a[mt] = zf; m2b[mt] = zf; }
    const int nt0 = wav * 2, nt1 = nt0 + 1;

    // ---- two-phase MLP1 (19->256) + MLP2 (256->128), hall = 128-col half ----
    #pragma unroll
    for (int ph = 0; ph < 2; ++ph) {
        #pragma unroll
        for (int ntl = 0; ntl < 2; ++ntl) {
            int ntg = ph * 8 + wav * 2 + ntl;     // global nt 0..15
            s16x8 wfr = *(const s16x8*)(wp + OFF_W1 + ntg * 512 + (lq * 16 + l15) * 8);
            int nloc = (wav * 2 + ntl) * 16 + lq * 4;   // col within half
            #pragma unroll
            for (int mt = 0; mt < 5; ++mt) {
                f32x4 acc = MFMA16(wfr, xfr[mt], zf);
                store_aff4(hallp, 80, mt * 16 + l15, nloc, acc, zf, true);
            }
        }
        __syncthreads();
        #pragma unroll
        for (int ktl = 0; ktl < 4; ++ktl) {
            int ktg = ph * 4 + ktl;
            s16x8 wf0 = *(const s16x8*)(wp + OFF_W2 + (nt0 * 8 + ktg) * 512 + (lq * 16 + l15) * 8);
            s16x8 wf1 = *(const s16x8*)(wp + OFF_W2 + (nt1 * 8 + ktg) * 512 + (lq * 16 + l15) * 8);
            #pragma unroll
            for (int mt = 0; mt < 5; ++mt) {
                s16x8 a = frag_aff(hallp, 80, mt * 16 + l15, ktl * 32 + lq * 8);
                m2a[mt] = MFMA16(wf0, a, m2a[mt]);
                m2b[mt] = MFMA16(wf1, a, m2b[mt]);
            }
        }
        __syncthreads();   // hall reads done before next-phase overwrite
    }
    // MLP2 epilogue -> x (affine)
    {
        f32x4 bs0 = *(const f32x4*)(b2v + nt0 * 16 + lq * 4);
        f32x4 bs1 = *(const f32x4*)(b2v + nt1 * 16 + lq * 4);
        #pragma unroll
        for (int mt = 0; mt < 5; ++mt) {
            int m = mt * 16 + l15;
            store_aff4(xp, 84, m, nt0 * 16 + lq * 4, m2a[mt], bs0, true);
            store_aff4(xp, 84, m, nt1 * 16 + lq * 4, m2b[mt], bs1, true);
        }
    }
    __syncthreads();

    // ---- stage 4: t = x@M + w' (Q/K folded; 1/sqrt(128) inside M,w') ----
    {
        const float* wf = (const float*)(wp + OFF_WP);
        f32x4 a0[5], a1[5];
        #pragma unroll
        for (int mt = 0; mt < 5; ++mt) { a0[mt] = zf; a1[mt] = zf; }
        #pragma unroll
        for (int kt = 0; kt < 4; ++kt) {
            s16x8 wf0 = *(const s16x8*)(wp + OFF_M + (nt0 * 4 + kt) * 512 + (lq * 16 + l15) * 8);
            s16x8 wf1 = *(const s16x8*)(wp + OFF_M + (nt1 * 4 + kt) * 512 + (lq * 16 + l15) * 8);
            #pragma unroll
            for (int mt = 0; mt < 5; ++mt) {
                s16x8 a = frag_aff(xp, 84, mt * 16 + l15, kt * 32 + lq * 8);
                a0[mt] = MFMA16(wf0, a, a0[mt]);
                a1[mt] = MFMA16(wf1, a, a1[mt]);
            }
        }
        f32x4 bs0 = *(const f32x4*)(wf + nt0 * 16 + lq * 4);
        f32x4 bs1 = *(const f32x4*)(wf + nt1 * 16 + lq * 4);
        #pragma unroll
        for (int mt = 0; mt < 5; ++mt) {
            int m = mt * 16 + l15;
            store_c4(&rB.t[0][0], m, DMP, nt0 * 16 + lq * 4, 15, a0[mt], bs0, false);
            store_c4(&rB.t[0][0], m, DMP, nt1 * 16 + lq * 4, 15, a1[mt], bs1, false);
        }
    }
    __syncthreads();

    // ---- stage 5: scores'[p][q] = t_p . x_q  (wave bi owns sc[bi]) ----
    {
        const int bi = wav;
        const int r0 = bi * N_PERM;
        int r1 = r0 + 16 + l15;
        if (r1 > 83) r1 = 83;     // rows >79 are garbage-masked; clamp keeps read in-bounds
        f32x4 c00 = zf, c01 = zf, c10 = zf, c11 = zf;
        #pragma unroll
        for (int kt = 0; kt < 4; ++kt) {
            int kof = kt * 32 + lq * 8;
            s16x8 a0 = frag_lds(&rB.t[0][0], r0 + l15,      DMP, kof, 15);
            s16x8 a1 = frag_lds(&rB.t[0][0], r0 + 16 + l15, DMP, kof, 15);  // garbage rows masked
            s16x8 k0 = frag_aff(xp, 84, r0 + l15, kof);
            s16x8 k1 = frag_aff(xp, 84, r1,       kof);
            c00 = MFMA16(a0, k0, c00);  c01 = MFMA16(a0, k1, c01);
            c10 = MFMA16(a1, k0, c10);  c11 = MFMA16(a1, k1, c11);
        }
        #pragma unroll
        for (int r = 0; r < 4; ++r) {
            int pr = lq * 4 + r, qc = l15;
            rA.p.sc[bi][pr][qc] = c00[r];
            if (qc + 16 < N_PERM) rA.p.sc[bi][pr][qc + 16] = c01[r];
            if (pr + 16 < N_PERM) {
                rA.p.sc[bi][pr + 16][qc] = c10[r];
                if (qc + 16 < N_PERM) rA.p.sc[bi][pr + 16][qc + 16] = c11[r];
            }
        }
    }
    // no barrier: stages 5..7 wave-private per bi

    // ---- stage 6: row softmax (lane = row), then column sums ----
    if (lane < N_PERM) {
        float* scrow = rA.p.sc[wav][lane];
        float mx = -1e30f;
        #pragma unroll
        for (int qq = 0; qq < N_PERM; ++qq) mx = fmaxf(mx, scrow[qq]);
        float sum = 0.f;
        #pragma unroll
        for (int qq = 0; qq < N_PERM; ++qq) { float e = __expf(scrow[qq] - mx); scrow[qq] = e; sum += e; }
        float inv = 1.f / sum;
        #pragma unroll
        for (int qq = 0; qq < N_PERM; ++qq) scrow[qq] *= inv;
    }
    if (lane < N_PERM) {
        float cs = 0.f;
        #pragma unroll
        for (int p = 0; p < N_PERM; ++p) cs += rA.p.sc[wav][p][lane];
        rA.p.cs[wav][lane] = cs;
    }

    // ---- stage 7: y[bi] = sum_q cs[q] * x[bi*20+q]  (V-GEMM eliminated) ----
    {
        int bi = wav, j0 = lane * 2;
        int kb = j0 >> 3, jo = j0 & 7;
        float a0 = 0.f, a1 = 0.f;
        #pragma unroll
        for (int qq = 0; qq < N_PERM; ++qq) {
            int row = bi * N_PERM + qq;
            unsigned w = *(const unsigned*)(xp + (kb * 84 + row) * 8 + jo);
            float c = rA.p.cs[bi][qq];
            a0 += c * __uint_as_float(w << 16);
            a1 += c * __uint_as_float(w & 0xffff0000u);
        }
        *(unsigned*)(yp + (kb * 16 + bi) * 8 + jo) = pkbf(a0, a1);
    }
    __syncthreads();

    // ---- stage 8: hr = relu(y@Wvr + bvr)  (Wv,Wr composed) ----
    {
        s16x8 pfr[4];
        #pragma unroll
        for (int kt = 0; kt < 4; ++kt)
            pfr[kt] = frag_aff(yp, 16, l15, kt * 32 + lq * 8);
        f32x4 acc[4];
        #pragma unroll
        for (int i = 0; i < 4; ++i) acc[i] = zf;
        #pragma unroll
        for (int kt = 0; kt < 4; ++kt)
            #pragma unroll
            for (int i = 0; i < 4; ++i) {
                int nt = wav * 4 + i;
                s16x8 wf = *(const s16x8*)(wp + OFF_WVR + (nt * 4 + kt) * 512 + (lq * 16 + l15) * 8);
                acc[i] = MFMA16(wf, pfr[kt], acc[i]);
            }
        const float* bvr = (const float*)(wp + OFF_BVR);
        #pragma unroll
        for (int i = 0; i < 4; ++i) {
            int n0 = (wav * 4 + i) * 16 + lq * 4;
            f32x4 bs = *(const f32x4*)(bvr + n0);
            store_aff4(hrp, 16, l15, n0, acc[i], bs, true);
        }
    }
    __syncthreads();

    // ---- stage 9: heads via MFMA on wave 0: D^T = Wh^T . hr^T (K=256, 8 kt) ----
    if (wav == 0) {
        f32x4 acc = zf;
        #pragma unroll
        for (int kt = 0; kt < 8; ++kt) {
            s16x8 wh = *(const s16x8*)(wp + OFF_WH + kt * 512 + (lq * 16 + l15) * 8);
            s16x8 hf = frag_aff(hrp, 16, l15, kt * 32 + lq * 8);
            acc = MFMA16(wh, hf, acc);
        }
        // C layout: col = l15 = bi (valid <TB); row = lq*4+r = head output o (valid lq<2)
        if (l15 < TB && lq < 2) {
            int bi = l15;
            if (lq == 0) {
                #pragma unroll
                for (int r = 0; r < 4; ++r)
                    out[(b0 + bi) * ACT + r] = acc[r] + bm[r];
            } else {
                #pragma unroll
                for (int r = 0; r < 4; ++r) {
                    float v = acc[r] + bsv[r];
                    out[BATCH * ACT + (b0 + bi) * ACT + r] = fminf(fmaxf(v, -20.f), 2.f);
                }
            }
        }
    }
}

extern "C" void kernel_launch(void* const* d_in, const int* in_sizes, int n_in,
                              void* d_out, int out_size, void* d_ws, size_t ws_size,
                              hipStream_t stream) {
    (void)in_sizes; (void)n_in; (void)out_size; (void)ws_size;
    const float* obs = (const float*)d_in[0];
    const float* ag  = (const float*)d_in[1];
    const float* g   = (const float*)d_in[2];
    const float* W1  = (const float*)d_in[3];
    const float* b1  = (const float*)d_in[4];
    const float* W2  = (const float*)d_in[5];
    const float* b2  = (const float*)d_in[6];
    const float* Wq  = (const float*)d_in[7];
    const float* bq  = (const float*)d_in[8];
    const float* Wk  = (const float*)d_in[9];
    const float* Wv  = (const float*)d_in[11];
    const float* bv  = (const float*)d_in[12];
    const float* Wr  = (const float*)d_in[13];
    const float* br  = (const float*)d_in[14];
    const float* Wm  = (const float*)d_in[15];
    const float* bm  = (const float*)d_in[16];
    const float* Ws  = (const float*)d_in[17];
    const float* bs  = (const float*)d_in[18];
    const int*  edges    = (const int*)d_in[19];
    const int*  pred_ids = (const int*)d_in[20];
    float* out = (float*)d_out;
    bf16*  wp  = (bf16*)d_ws;

    prepack_kernel<<<(PACK_TOTAL + 255) / 256, 256, 0, stream>>>(
        W1, b1, W2, Wq, bq, Wk, Wv, bv, Wr, br, Wm, Ws, edges, pred_ids, wp);
    actor_main<<<BATCH / TB, 256, 0, stream>>>(
        obs, ag, g, b2, bm, bs, wp, out);
}

// Round 16
// 241.920 us; speedup vs baseline: 1.0188x; 1.0188x over previous
//
#include <hip/hip_runtime.h>
#include <hip/hip_bf16.h>

#define NB_OBJ   5
#define DIM_BODY 10
#define DIM_OBJ  15
#define N_PERM   20
#define HID      256
#define DMP      128
#define ACT      4
#define BATCH    32768
#define GOAL_DIM 30
#define DIN      19
#define OBS_LEN  85
#define TB       4                 // batch elements per block
#define MROWS    80                // TB * N_PERM, 5 M-tiles

typedef __hip_bfloat16 bf16;
typedef __attribute__((ext_vector_type(8))) short s16x8;
typedef __attribute__((ext_vector_type(4))) float f32x4;
typedef __attribute__((ext_vector_type(2))) unsigned u32x2;

#define MFMA16(a, b, c) __builtin_amdgcn_mfma_f32_16x16x32_bf16((a), (b), (c), 0, 0, 0)

// ---- packed-weight offsets in d_ws (bf16 element units) ----
// tiled: [nt][kt][c(4)][n16(16)][j(8)] = W[kt*32+c*8+j][nt*16+n16]
#define OFF_W1   0          // NT=16, KT=1 -> 8192 (k=19 row = b1 bias fold)
#define OFF_W2   8192       // NT=8,  KT=8 -> 32768
#define OFF_M    40960      // NT=8,  KT=4 -> 16384   M = Wq Wk^T / sqrt(128)
#define OFF_WVR  57344      // NT=16, KT=4 -> 32768   Wvr = Wv @ Wr (no relu between)
#define OFF_WP   90112      // 128 f32 (w' = Wk bq / sqrt(128)) -> 256 slots
#define OFF_BVR  90368      // 256 f32 (bvr = 20*bv@Wr + br) -> 512 slots
#define OFF_WH   90880      // head weights [Wm|Ws] as A-frag tiles, KT=8 -> 4096
#define OFF_TBL  94976      // gather table tbl[20][32] int16 -> 640 slots
#define PACK_TOTAL 95232

// fast f32->bf16, round-half-up; tie-behavior-only delta vs RNE
__device__ __forceinline__ unsigned short bfr(float x) {
    return (unsigned short)((__float_as_uint(x) + 0x8000u) >> 16);
}
__device__ __forceinline__ unsigned pkbf(float a, float b) {
    return ((__float_as_uint(a) + 0x8000u) >> 16)
         | ((__float_as_uint(b) + 0x8000u) & 0xffff0000u);
}

// XOR block swizzle: element [m][k] at column ((k>>3)^(m&bprm))*8 + (k&7)
// (R15 lesson: affine k-block layouts save the XOR VALU but their k-block
//  stride aligns to 0 mod 128 B -> 4-way b64 store conflicts; XOR is net better)
__device__ __forceinline__ s16x8 frag_lds(const bf16* base, int m, int stride, int kof, int bprm) {
    int phys = (((kof >> 3) ^ (m & bprm)) << 3);
    return *(const s16x8*)(base + m * stride + phys);
}

// C^T epilogue: lane owns fixed m, regs = 4 consecutive n -> one b64 write
__device__ __forceinline__ void store_c4(bf16* base, int m, int stride, int n0,
                                         int bprm, f32x4 acc, f32x4 bs, bool do_relu) {
    float v0 = acc[0] + bs[0], v1 = acc[1] + bs[1];
    float v2 = acc[2] + bs[2], v3 = acc[3] + bs[3];
    if (do_relu) {
        v0 = fmaxf(v0, 0.f); v1 = fmaxf(v1, 0.f);
        v2 = fmaxf(v2, 0.f); v3 = fmaxf(v3, 0.f);
    }
    u32x2 w;
    w.x = pkbf(v0, v1);
    w.y = pkbf(v2, v3);
    int blk = ((n0 >> 3) ^ (m & bprm));
    *(u32x2*)(base + m * stride + blk * 8 + (n0 & 7)) = w;
}

// ================= prepack =================
__device__ __forceinline__ void pack_tiled(const float* __restrict__ W, int Kact, int N,
                                           int KT, bf16* __restrict__ dst, int idx) {
    int tile = idx >> 9;
    int r    = idx & 511;
    int kt   = tile % KT, nt = tile / KT;
    int c    = r >> 7;
    int rem  = r & 127;
    int n16  = rem >> 3, j = rem & 7;
    int k    = kt * 32 + c * 8 + j;
    float v  = (k < Kact) ? W[k * N + nt * 16 + n16] : 0.f;
    dst[idx] = __float2bfloat16(v);
}

__global__ __launch_bounds__(256) void prepack_kernel(
    const float* __restrict__ W1, const float* __restrict__ b1,
    const float* __restrict__ W2,
    const float* __restrict__ Wq, const float* __restrict__ bq,
    const float* __restrict__ Wk,
    const float* __restrict__ Wv, const float* __restrict__ bv,
    const float* __restrict__ Wr, const float* __restrict__ br,
    const float* __restrict__ Wm, const float* __restrict__ Wsc,
    const int* __restrict__ edges, const int* __restrict__ pred_ids,
    bf16* __restrict__ ws) {
    const float scl = 0.08838834764831845f;   // 1/sqrt(128)
    int idx = blockIdx.x * 256 + threadIdx.x;
    if (idx < 8192) {               // W1 with bias folded into k=19
        int nt = idx >> 9, r = idx & 511;
        int c = r >> 7, rem = r & 127, n16 = rem >> 3, j = rem & 7;
        int k = c * 8 + j, n = nt * 16 + n16;
        float v = (k < DIN) ? W1[k * HID + n] : (k == DIN ? b1[n] : 0.f);
        ws[OFF_W1 + idx] = __float2bfloat16(v);
    }
    else if (idx < 40960) pack_tiled(W2, 256, 128, 8, ws + OFF_W2, idx - 8192);
    else if (idx < 57344) {         // M = Wq Wk^T * scl, fragment-tiled, float4 dot
        int i2 = idx - 40960;
        int tile = i2 >> 9, r = i2 & 511;
        int kt = tile & 3, nt = tile >> 2;
        int c = r >> 7, rem = r & 127, n16 = rem >> 3, j = rem & 7;
        int d = kt * 32 + c * 8 + j;        // contraction dim of t = x@M
        int e = nt * 16 + n16;              // output dim
        const float4* qr = (const float4*)(Wq + d * DMP);
        const float4* kr = (const float4*)(Wk + e * DMP);
        float s = 0.f;
        #pragma unroll 8
        for (int t = 0; t < 32; ++t) {
            float4 a = qr[t], b = kr[t];
            s += a.x * b.x + a.y * b.y + a.z * b.z + a.w * b.w;
        }
        ws[OFF_M + i2] = __float2bfloat16(s * scl);
    }
    else if (idx < 90112) {         // WVR = Wv @ Wr (K=128, N=256, KT=4)
        int i2 = idx - 57344;
        int tile = i2 >> 9, r = i2 & 511;
        int kt = tile & 3, nt = tile >> 2;
        int c = r >> 7, rem = r & 127, n16 = rem >> 3, j = rem & 7;
        int k = kt * 32 + c * 8 + j;        // contraction dim of hr = y@Wvr
        int n = nt * 16 + n16;              // output dim (0..255)
        const float* vr = Wv + k * DMP;
        float s = 0.f;
        #pragma unroll 8
        for (int j2 = 0; j2 < DMP; ++j2) s += vr[j2] * Wr[j2 * HID + n];
        ws[OFF_WVR + i2] = __float2bfloat16(s);
    }
    else if (idx < 90240) {         // w'[d] = scl * (Wk row d . bq)
        int d = idx - 90112;
        const float4* kr = (const float4*)(Wk + d * DMP);
        const float4* bq4 = (const float4*)bq;
        float s = 0.f;
        #pragma unroll 8
        for (int t = 0; t < 32; ++t) {
            float4 a = kr[t], b = bq4[t];
            s += a.x * b.x + a.y * b.y + a.z * b.z + a.w * b.w;
        }
        ((float*)(ws + OFF_WP))[d] = s * scl;
    }
    else if (idx < 90496) {         // bvr[n] = 20 * (bv . Wr[:,n]) + br[n]
        int n = idx - 90240;
        float s = 0.f;
        #pragma unroll 8
        for (int j2 = 0; j2 < DMP; ++j2) s += bv[j2] * Wr[j2 * HID + n];
        ((float*)(ws + OFF_BVR))[n] = 20.f * s + br[n];
    }
    else if (idx < 94592) {         // WH: [Wm|Ws] packed as A-frag tiles (o = m index)
        int i2 = idx - 90496;
        int kt = i2 >> 9, r = i2 & 511;
        int c = r >> 7, rem = r & 127, o = rem >> 3, j = rem & 7;
        int k = kt * 32 + c * 8 + j;
        float v = (o < ACT) ? Wm[k * ACT + o]
                : (o < 2 * ACT) ? Wsc[k * ACT + (o - ACT)] : 0.f;
        ws[OFF_WH + i2] = __float2bfloat16(v);
    }
    else if (idx < PACK_TOTAL) {    // gather table tbl[p][c], c in [0,32)
        int i2 = idx - 94592;
        int p = i2 >> 5, c = i2 & 31;
        short t;
        if      (c < 10) t = (short)c;
        else if (c < 13) t = (short)(OBS_LEN + pred_ids[p * 3 + (c - 10)]);
        else if (c < 16) t = (short)(DIM_BODY + edges[p * 2 + 0] * DIM_OBJ + (c - 13));
        else if (c < 19) t = (short)(DIM_BODY + edges[p * 2 + 1] * DIM_OBJ + (c - 16));
        else if (c == 19) t = 115;  // flat slot holding 1.0 (W1 bias row)
        else              t = 116;  // flat slot holding 0.0 (K pad)
        ((short*)(ws + OFF_TBL))[i2] = t;
    }
}

// ================= main fused kernel =================
// LDS: rA 10,816 + rB 20,480 + rC 20,480 = 51,776 B -> 3 blocks/CU
__global__ __launch_bounds__(256, 3) void actor_main(
    const float* __restrict__ obs, const float* __restrict__ ag, const float* __restrict__ g,
    const float* __restrict__ b2v,
    const float* __restrict__ bm, const float* __restrict__ bsv,
    const bf16* __restrict__ wp, float* __restrict__ out)
{
    const int b0   = blockIdx.x * TB;
    const int tid  = threadIdx.x;
    const int lane = tid & 63;
    const int wav  = tid >> 6;
    const int l15  = lane & 15;
    const int lq   = lane >> 4;

    __shared__ __align__(16) union {              // 10,816 B
        struct {
            float flat[TB][120];                  // [0..84]=obs [85..114]=dg [115]=1 [116..]=0
            short tbl[N_PERM * 32];
            bf16  inp[MROWS][40];                 // K pad 19->32 (+bias col via tbl)
        } a;                                      // 9,600 (dead after xfr loads)
        struct {
            float sc[TB][N_PERM][N_PERM];         // 6,400
            float cs[TB][N_PERM];                 // 320
            bf16  y[16][DMP];                     // 4,096 (swizzled; rows TB..15 stale, masked)
        } p;                                      // 10,816
    } rA;
    __shared__ __align__(16) union {              // 20,480 B
        bf16 hall[MROWS][DMP];                    // one 128-col half of MLP1 out
        bf16 t[MROWS][DMP];                       // t = x@M + w' (after MLP2)
    } rB;
    __shared__ __align__(16) union {              // 20,480 B
        bf16 x[MROWS][DMP];                       // edge_feat (dead after y)
        bf16 hr[16][HID];                         // 8,192 (swizzled; rows TB..15 garbage)
    } rC;

    const f32x4 zf = {0.f, 0.f, 0.f, 0.f};

    // ---- stage 0: flat input vector + gather table -> LDS ----
    for (int i = tid; i < TB * 120; i += 256) {
        int bi = i / 120, c = i - bi * 120;
        float v = 0.f;
        if      (c < OBS_LEN) v = obs[(b0 + bi) * OBS_LEN + c];
        else if (c < 115)     v = g[(b0 + bi) * GOAL_DIM + (c - OBS_LEN)]
                                - ag[(b0 + bi) * GOAL_DIM + (c - OBS_LEN)];
        else if (c == 115)    v = 1.0f;
        rA.a.flat[bi][c] = v;
    }
    for (int i = tid; i < N_PERM * 32; i += 256)
        ((short*)rA.a.tbl)[i] = ((const short*)(wp + OFF_TBL))[i];
    __syncthreads();

    // ---- stage 1: build 80 x 32 edge inputs via gather table ----
    for (int idx = tid; idx < MROWS * 32; idx += 256) {
        int m = idx >> 5, c = idx & 31;
        int bi = m / N_PERM, p = m - bi * N_PERM;
        float v = rA.a.flat[bi][rA.a.tbl[p * 32 + c]];
        *(unsigned short*)&rA.a.inp[m][c] = bfr(v);
    }
    __syncthreads();

    // MLP1 input fragments (live across both phases)
    s16x8 xfr[5];
    #pragma unroll
    for (int mt = 0; mt < 5; ++mt)
        xfr[mt] = *(const s16x8*)(&rA.a.inp[mt * 16 + l15][lq * 8]);

    // MLP2 accumulators (live across both phases)
    f32x4 m2a[5], m2b[5];
    #pragma unroll
    for (int mt = 0; mt < 5; ++mt) { m2a[mt] = zf; m2b[mt] = zf; }
    const int nt0 = wav * 2, nt1 = nt0 + 1;

    // ---- two-phase MLP1 (19->256) + MLP2 (256->128), hall = 128-col half ----
    #pragma unroll
    for (int ph = 0; ph < 2; ++ph) {
        #pragma unroll
        for (int ntl = 0; ntl < 2; ++ntl) {
            int ntg = ph * 8 + wav * 2 + ntl;     // global nt 0..15
            s16x8 wfr = *(const s16x8*)(wp + OFF_W1 + ntg * 512 + (lq * 16 + l15) * 8);
            int nloc = (wav * 2 + ntl) * 16 + lq * 4;   // col within half
            #pragma unroll
            for (int mt = 0; mt < 5; ++mt) {
                f32x4 acc = MFMA16(wfr, xfr[mt], zf);
                store_c4(&rB.hall[0][0], mt * 16 + l15, DMP, nloc, 15, acc, zf, true);
            }
        }
        __syncthreads();
        #pragma unroll
        for (int ktl = 0; ktl < 4; ++ktl) {
            int ktg = ph * 4 + ktl;
            s16x8 wf0 = *(const s16x8*)(wp + OFF_W2 + (nt0 * 8 + ktg) * 512 + (lq * 16 + l15) * 8);
            s16x8 wf1 = *(const s16x8*)(wp + OFF_W2 + (nt1 * 8 + ktg) * 512 + (lq * 16 + l15) * 8);
            #pragma unroll
            for (int mt = 0; mt < 5; ++mt) {
                s16x8 a = frag_lds(&rB.hall[0][0], mt * 16 + l15, DMP, ktl * 32 + lq * 8, 15);
                m2a[mt] = MFMA16(wf0, a, m2a[mt]);
                m2b[mt] = MFMA16(wf1, a, m2b[mt]);
            }
        }
        // barrier only between ph0's hall reads and ph1's hall overwrite.
        // ph1-exit barrier removed (R16): ph1 MLP2 reads rB.hall, next writes
        // are x (rC) then a sync before stage-4's t (rB) overwrite — all
        // cross-wave hazards ordered by that sync.
        if (ph == 0) __syncthreads();
    }
    // MLP2 epilogue -> x
    {
        f32x4 bs0 = *(const f32x4*)(b2v + nt0 * 16 + lq * 4);
        f32x4 bs1 = *(const f32x4*)(b2v + nt1 * 16 + lq * 4);
        #pragma unroll
        for (int mt = 0; mt < 5; ++mt) {
            int m = mt * 16 + l15;
            store_c4(&rC.x[0][0], m, DMP, nt0 * 16 + lq * 4, 15, m2a[mt], bs0, true);
            store_c4(&rC.x[0][0], m, DMP, nt1 * 16 + lq * 4, 15, m2b[mt], bs1, true);
        }
    }
    __syncthreads();

    // ---- stage 4: t = x@M + w' (Q/K folded; 1/sqrt(128) inside M,w') ----
    {
        const float* wf = (const float*)(wp + OFF_WP);
        f32x4 a0[5], a1[5];
        #pragma unroll
        for (int mt = 0; mt < 5; ++mt) { a0[mt] = zf; a1[mt] = zf; }
        #pragma unroll
        for (int kt = 0; kt < 4; ++kt) {
            s16x8 wf0 = *(const s16x8*)(wp + OFF_M + (nt0 * 4 + kt) * 512 + (lq * 16 + l15) * 8);
            s16x8 wf1 = *(const s16x8*)(wp + OFF_M + (nt1 * 4 + kt) * 512 + (lq * 16 + l15) * 8);
            #pragma unroll
            for (int mt = 0; mt < 5; ++mt) {
                s16x8 a = frag_lds(&rC.x[0][0], mt * 16 + l15, DMP, kt * 32 + lq * 8, 15);
                a0[mt] = MFMA16(wf0, a, a0[mt]);
                a1[mt] = MFMA16(wf1, a, a1[mt]);
            }
        }
        f32x4 bs0 = *(const f32x4*)(wf + nt0 * 16 + lq * 4);
        f32x4 bs1 = *(const f32x4*)(wf + nt1 * 16 + lq * 4);
        #pragma unroll
        for (int mt = 0; mt < 5; ++mt) {
            int m = mt * 16 + l15;
            store_c4(&rB.t[0][0], m, DMP, nt0 * 16 + lq * 4, 15, a0[mt], bs0, false);
            store_c4(&rB.t[0][0], m, DMP, nt1 * 16 + lq * 4, 15, a1[mt], bs1, false);
        }
    }
    __syncthreads();

    // ---- stage 5: scores'[p][q] = t_p . x_q  (wave bi owns sc[bi]) ----
    {
        const int bi = wav;
        const int r0 = bi * N_PERM;
        f32x4 c00 = zf, c01 = zf, c10 = zf, c11 = zf;
        #pragma unroll
        for (int kt = 0; kt < 4; ++kt) {
            int kof = kt * 32 + lq * 8;
            s16x8 a0 = frag_lds(&rB.t[0][0], r0 + l15,      DMP, kof, 15);
            s16x8 a1 = frag_lds(&rB.t[0][0], r0 + 16 + l15, DMP, kof, 15);  // rows>79 garbage, masked
            s16x8 k0 = frag_lds(&rC.x[0][0], r0 + l15,      DMP, kof, 15);
            s16x8 k1 = frag_lds(&rC.x[0][0], r0 + 16 + l15, DMP, kof, 15);
            c00 = MFMA16(a0, k0, c00);  c01 = MFMA16(a0, k1, c01);
            c10 = MFMA16(a1, k0, c10);  c11 = MFMA16(a1, k1, c11);
        }
        #pragma unroll
        for (int r = 0; r < 4; ++r) {
            int pr = lq * 4 + r, qc = l15;
            rA.p.sc[bi][pr][qc] = c00[r];
            if (qc + 16 < N_PERM) rA.p.sc[bi][pr][qc + 16] = c01[r];
            if (pr + 16 < N_PERM) {
                rA.p.sc[bi][pr + 16][qc] = c10[r];
                if (qc + 16 < N_PERM) rA.p.sc[bi][pr + 16][qc + 16] = c11[r];
            }
        }
    }
    // no barrier: stages 5..7 wave-private per bi

    // ---- stage 6: row softmax (lane = row), then column sums ----
    if (lane < N_PERM) {
        float* scrow = rA.p.sc[wav][lane];
        float mx = -1e30f;
        #pragma unroll
        for (int qq = 0; qq < N_PERM; ++qq) mx = fmaxf(mx, scrow[qq]);
        float sum = 0.f;
        #pragma unroll
        for (int qq = 0; qq < N_PERM; ++qq) { float e = __expf(scrow[qq] - mx); scrow[qq] = e; sum += e; }
        float inv = 1.f / sum;
        #pragma unroll
        for (int qq = 0; qq < N_PERM; ++qq) scrow[qq] *= inv;
    }
    if (lane < N_PERM) {
        float cs = 0.f;
        #pragma unroll
        for (int p = 0; p < N_PERM; ++p) cs += rA.p.sc[wav][p][lane];
        rA.p.cs[wav][lane] = cs;
    }

    // ---- stage 7: y[bi] = sum_q cs[q] * x[bi*20+q]  (V-GEMM eliminated) ----
    {
        int bi = wav, j0 = lane * 2;
        float a0 = 0.f, a1 = 0.f;
        #pragma unroll
        for (int qq = 0; qq < N_PERM; ++qq) {
            int row  = bi * N_PERM + qq;
            int vcol = ((((j0 >> 3) ^ (row & 15)) << 3) | (j0 & 7));
            unsigned w = *(const unsigned*)(&rC.x[row][vcol]);
            float c = rA.p.cs[bi][qq];
            a0 += c * __uint_as_float(w << 16);
            a1 += c * __uint_as_float(w & 0xffff0000u);
        }
        int pcol = ((((j0 >> 3) ^ (bi & 15)) << 3) | (j0 & 7));
        *(unsigned*)(&rA.p.y[bi][pcol]) = pkbf(a0, a1);
    }
    __syncthreads();

    // ---- stage 8: hr = relu(y@Wvr + bvr)  (Wv,Wr composed) ----
    {
        s16x8 pfr[4];
        #pragma unroll
        for (int kt = 0; kt < 4; ++kt)
            pfr[kt] = frag_lds(&rA.p.y[0][0], l15, DMP, kt * 32 + lq * 8, 15);
        f32x4 acc[4];
        #pragma unroll
        for (int i = 0; i < 4; ++i) acc[i] = zf;
        #pragma unroll
        for (int kt = 0; kt < 4; ++kt)
            #pragma unroll
            for (int i = 0; i < 4; ++i) {
                int nt = wav * 4 + i;
                s16x8 wf = *(const s16x8*)(wp + OFF_WVR + (nt * 4 + kt) * 512 + (lq * 16 + l15) * 8);
                acc[i] = MFMA16(wf, pfr[kt], acc[i]);
            }
        const float* bvr = (const float*)(wp + OFF_BVR);
        #pragma unroll
        for (int i = 0; i < 4; ++i) {
            int n0 = (wav * 4 + i) * 16 + lq * 4;
            f32x4 bs = *(const f32x4*)(bvr + n0);
            store_c4(&rC.hr[0][0], l15, HID, n0, 15, acc[i], bs, true);
        }
    }
    __syncthreads();

    // ---- stage 9: heads via MFMA on wave 0: D^T = Wh^T . hr^T (K=256, 8 kt) ----
    if (wav == 0) {
        f32x4 acc = zf;
        #pragma unroll
        for (int kt = 0; kt < 8; ++kt) {
            s16x8 wh = *(const s16x8*)(wp + OFF_WH + kt * 512 + (lq * 16 + l15) * 8);
            s16x8 hf = frag_lds(&rC.hr[0][0], l15, HID, kt * 32 + lq * 8, 15);
            acc = MFMA16(wh, hf, acc);
        }
        // C layout: col = l15 = bi (valid <TB); row = lq*4+r = head output o (valid lq<2)
        if (l15 < TB && lq < 2) {
            int bi = l15;
            if (lq == 0) {
                #pragma unroll
                for (int r = 0; r < 4; ++r)
                    out[(b0 + bi) * ACT + r] = acc[r] + bm[r];
            } else {
                #pragma unroll
                for (int r = 0; r < 4; ++r) {
                    float v = acc[r] + bsv[r];
                    out[BATCH * ACT + (b0 + bi) * ACT + r] = fminf(fmaxf(v, -20.f), 2.f);
                }
            }
        }
    }
}

extern "C" void kernel_launch(void* const* d_in, const int* in_sizes, int n_in,
                              void* d_out, int out_size, void* d_ws, size_t ws_size,
                              hipStream_t stream) {
    (void)in_sizes; (void)n_in; (void)out_size; (void)ws_size;
    const float* obs = (const float*)d_in[0];
    const float* ag  = (const float*)d_in[1];
    const float* g   = (const float*)d_in[2];
    const float* W1  = (const float*)d_in[3];
    const float* b1  = (const float*)d_in[4];
    const float* W2  = (const float*)d_in[5];
    const float* b2  = (const float*)d_in[6];
    const float* Wq  = (const float*)d_in[7];
    const float* bq  = (const float*)d_in[8];
    const float* Wk  = (const float*)d_in[9];
    const float* Wv  = (const float*)d_in[11];
    const float* bv  = (const float*)d_in[12];
    const float* Wr  = (const float*)d_in[13];
    const float* br  = (const float*)d_in[14];
    const float* Wm  = (const float*)d_in[15];
    const float* bm  = (const float*)d_in[16];
    const float* Ws  = (const float*)d_in[17];
    const float* bs  = (const float*)d_in[18];
    const int*  edges    = (const int*)d_in[19];
    const int*  pred_ids = (const int*)d_in[20];
    float* out = (float*)d_out;
    bf16*  wp  = (bf16*)d_ws;

    prepack_kernel<<<(PACK_TOTAL + 255) / 256, 256, 0, stream>>>(
        W1, b1, W2, Wq, bq, Wk, Wv, bv, Wr, br, Wm, Ws, edges, pred_ids, wp);
    actor_main<<<BATCH / TB, 256, 0, stream>>>(
        obs, ag, g, b2, bm, bs, wp, out);
}

// Round 17
// 240.452 us; speedup vs baseline: 1.0251x; 1.0061x over previous
//
#include <hip/hip_runtime.h>
#include <hip/hip_bf16.h>

#define NB_OBJ   5
#define DIM_BODY 10
#define DIM_OBJ  15
#define N_PERM   20
#define HID      256
#define DMP      128
#define ACT      4
#define BATCH    32768
#define GOAL_DIM 30
#define DIN      19
#define OBS_LEN  85
#define TB       4                 // batch elements per block
#define MROWS    80                // TB * N_PERM, 5 M-tiles

typedef __hip_bfloat16 bf16;
typedef __attribute__((ext_vector_type(8))) short s16x8;
typedef __attribute__((ext_vector_type(4))) float f32x4;
typedef __attribute__((ext_vector_type(2))) unsigned u32x2;

#define MFMA16(a, b, c) __builtin_amdgcn_mfma_f32_16x16x32_bf16((a), (b), (c), 0, 0, 0)

// ---- packed-weight offsets in d_ws (bf16 element units) ----
// tiled: [nt][kt][c(4)][n16(16)][j(8)] = W[kt*32+c*8+j][nt*16+n16]
#define OFF_W1   0          // NT=16, KT=1 -> 8192 (k=19 row = b1 bias fold)
#define OFF_W2   8192       // NT=8,  KT=8 -> 32768
#define OFF_M    40960      // NT=8,  KT=4 -> 16384   M = Wq Wk^T / sqrt(128)
#define OFF_WVR  57344      // NT=16, KT=4 -> 32768   Wvr = Wv @ Wr (no relu between)
#define OFF_WP   90112      // 128 f32 (w' = Wk bq / sqrt(128)) -> 256 slots
#define OFF_BVR  90368      // 256 f32 (bvr = 20*bv@Wr + br) -> 512 slots
#define OFF_WH   90880      // head weights [Wm|Ws] as A-frag tiles, KT=8 -> 4096
#define OFF_TBL  94976      // gather table tbl[20][32] int16 -> 640 slots
#define PACK_TOTAL 95232

// fast f32->bf16 single (round-half-up; used only in stage-1 gather)
__device__ __forceinline__ unsigned short bfr(float x) {
    return (unsigned short)((__float_as_uint(x) + 0x8000u) >> 16);
}

// packed 2x f32 -> bf16x2. gfx950 has v_cvt_pk_bf16_f32 (ONE VALU op);
// fallback = bit trick (R11). R16->R17 single-variable change.
#if __has_builtin(__builtin_amdgcn_cvt_pk_bf16_f32)
__device__ __forceinline__ unsigned pkbf(float a, float b) {
    auto r = __builtin_amdgcn_cvt_pk_bf16_f32(a, b);
    return *(unsigned*)&r;
}
#else
__device__ __forceinline__ unsigned pkbf(float a, float b) {
    return ((__float_as_uint(a) + 0x8000u) >> 16)
         | ((__float_as_uint(b) + 0x8000u) & 0xffff0000u);
}
#endif

// XOR block swizzle: element [m][k] at column ((k>>3)^(m&bprm))*8 + (k&7)
// (R15 lesson: affine k-block layouts save the XOR VALU but their k-block
//  stride aligns to 0 mod 128 B -> 4-way b64 store conflicts; XOR is net better)
__device__ __forceinline__ s16x8 frag_lds(const bf16* base, int m, int stride, int kof, int bprm) {
    int phys = (((kof >> 3) ^ (m & bprm)) << 3);
    return *(const s16x8*)(base + m * stride + phys);
}

// C^T epilogue: lane owns fixed m, regs = 4 consecutive n -> one b64 write
__device__ __forceinline__ void store_c4(bf16* base, int m, int stride, int n0,
                                         int bprm, f32x4 acc, f32x4 bs, bool do_relu) {
    float v0 = acc[0] + bs[0], v1 = acc[1] + bs[1];
    float v2 = acc[2] + bs[2], v3 = acc[3] + bs[3];
    if (do_relu) {
        v0 = fmaxf(v0, 0.f); v1 = fmaxf(v1, 0.f);
        v2 = fmaxf(v2, 0.f); v3 = fmaxf(v3, 0.f);
    }
    u32x2 w;
    w.x = pkbf(v0, v1);
    w.y = pkbf(v2, v3);
    int blk = ((n0 >> 3) ^ (m & bprm));
    *(u32x2*)(base + m * stride + blk * 8 + (n0 & 7)) = w;
}

// ================= prepack =================
__device__ __forceinline__ void pack_tiled(const float* __restrict__ W, int Kact, int N,
                                           int KT, bf16* __restrict__ dst, int idx) {
    int tile = idx >> 9;
    int r    = idx & 511;
    int kt   = tile % KT, nt = tile / KT;
    int c    = r >> 7;
    int rem  = r & 127;
    int n16  = rem >> 3, j = rem & 7;
    int k    = kt * 32 + c * 8 + j;
    float v  = (k < Kact) ? W[k * N + nt * 16 + n16] : 0.f;
    dst[idx] = __float2bfloat16(v);
}

__global__ __launch_bounds__(256) void prepack_kernel(
    const float* __restrict__ W1, const float* __restrict__ b1,
    const float* __restrict__ W2,
    const float* __restrict__ Wq, const float* __restrict__ bq,
    const float* __restrict__ Wk,
    const float* __restrict__ Wv, const float* __restrict__ bv,
    const float* __restrict__ Wr, const float* __restrict__ br,
    const float* __restrict__ Wm, const float* __restrict__ Wsc,
    const int* __restrict__ edges, const int* __restrict__ pred_ids,
    bf16* __restrict__ ws) {
    const float scl = 0.08838834764831845f;   // 1/sqrt(128)
    int idx = blockIdx.x * 256 + threadIdx.x;
    if (idx < 8192) {               // W1 with bias folded into k=19
        int nt = idx >> 9, r = idx & 511;
        int c = r >> 7, rem = r & 127, n16 = rem >> 3, j = rem & 7;
        int k = c * 8 + j, n = nt * 16 + n16;
        float v = (k < DIN) ? W1[k * HID + n] : (k == DIN ? b1[n] : 0.f);
        ws[OFF_W1 + idx] = __float2bfloat16(v);
    }
    else if (idx < 40960) pack_tiled(W2, 256, 128, 8, ws + OFF_W2, idx - 8192);
    else if (idx < 57344) {         // M = Wq Wk^T * scl, fragment-tiled, float4 dot
        int i2 = idx - 40960;
        int tile = i2 >> 9, r = i2 & 511;
        int kt = tile & 3, nt = tile >> 2;
        int c = r >> 7, rem = r & 127, n16 = rem >> 3, j = rem & 7;
        int d = kt * 32 + c * 8 + j;        // contraction dim of t = x@M
        int e = nt * 16 + n16;              // output dim
        const float4* qr = (const float4*)(Wq + d * DMP);
        const float4* kr = (const float4*)(Wk + e * DMP);
        float s = 0.f;
        #pragma unroll 8
        for (int t = 0; t < 32; ++t) {
            float4 a = qr[t], b = kr[t];
            s += a.x * b.x + a.y * b.y + a.z * b.z + a.w * b.w;
        }
        ws[OFF_M + i2] = __float2bfloat16(s * scl);
    }
    else if (idx < 90112) {         // WVR = Wv @ Wr (K=128, N=256, KT=4)
        int i2 = idx - 57344;
        int tile = i2 >> 9, r = i2 & 511;
        int kt = tile & 3, nt = tile >> 2;
        int c = r >> 7, rem = r & 127, n16 = rem >> 3, j = rem & 7;
        int k = kt * 32 + c * 8 + j;        // contraction dim of hr = y@Wvr
        int n = nt * 16 + n16;              // output dim (0..255)
        const float* vr = Wv + k * DMP;
        float s = 0.f;
        #pragma unroll 8
        for (int j2 = 0; j2 < DMP; ++j2) s += vr[j2] * Wr[j2 * HID + n];
        ws[OFF_WVR + i2] = __float2bfloat16(s);
    }
    else if (idx < 90240) {         // w'[d] = scl * (Wk row d . bq)
        int d = idx - 90112;
        const float4* kr = (const float4*)(Wk + d * DMP);
        const float4* bq4 = (const float4*)bq;
        float s = 0.f;
        #pragma unroll 8
        for (int t = 0; t < 32; ++t) {
            float4 a = kr[t], b = bq4[t];
            s += a.x * b.x + a.y * b.y + a.z * b.z + a.w * b.w;
        }
        ((float*)(ws + OFF_WP))[d] = s * scl;
    }
    else if (idx < 90496) {         // bvr[n] = 20 * (bv . Wr[:,n]) + br[n]
        int n = idx - 90240;
        float s = 0.f;
        #pragma unroll 8
        for (int j2 = 0; j2 < DMP; ++j2) s += bv[j2] * Wr[j2 * HID + n];
        ((float*)(ws + OFF_BVR))[n] = 20.f * s + br[n];
    }
    else if (idx < 94592) {         // WH: [Wm|Ws] packed as A-frag tiles (o = m index)
        int i2 = idx - 90496;
        int kt = i2 >> 9, r = i2 & 511;
        int c = r >> 7, rem = r & 127, o = rem >> 3, j = rem & 7;
        int k = kt * 32 + c * 8 + j;
        float v = (o < ACT) ? Wm[k * ACT + o]
                : (o < 2 * ACT) ? Wsc[k * ACT + (o - ACT)] : 0.f;
        ws[OFF_WH + i2] = __float2bfloat16(v);
    }
    else if (idx < PACK_TOTAL) {    // gather table tbl[p][c], c in [0,32)
        int i2 = idx - 94592;
        int p = i2 >> 5, c = i2 & 31;
        short t;
        if      (c < 10) t = (short)c;
        else if (c < 13) t = (short)(OBS_LEN + pred_ids[p * 3 + (c - 10)]);
        else if (c < 16) t = (short)(DIM_BODY + edges[p * 2 + 0] * DIM_OBJ + (c - 13));
        else if (c < 19) t = (short)(DIM_BODY + edges[p * 2 + 1] * DIM_OBJ + (c - 16));
        else if (c == 19) t = 115;  // flat slot holding 1.0 (W1 bias row)
        else              t = 116;  // flat slot holding 0.0 (K pad)
        ((short*)(ws + OFF_TBL))[i2] = t;
    }
}

// ================= main fused kernel =================
// LDS: rA 10,816 + rB 20,480 + rC 20,480 = 51,776 B -> 3 blocks/CU
__global__ __launch_bounds__(256, 3) void actor_main(
    const float* __restrict__ obs, const float* __restrict__ ag, const float* __restrict__ g,
    const float* __restrict__ b2v,
    const float* __restrict__ bm, const float* __restrict__ bsv,
    const bf16* __restrict__ wp, float* __restrict__ out)
{
    const int b0   = blockIdx.x * TB;
    const int tid  = threadIdx.x;
    const int lane = tid & 63;
    const int wav  = tid >> 6;
    const int l15  = lane & 15;
    const int lq   = lane >> 4;

    __shared__ __align__(16) union {              // 10,816 B
        struct {
            float flat[TB][120];                  // [0..84]=obs [85..114]=dg [115]=1 [116..]=0
            short tbl[N_PERM * 32];
            bf16  inp[MROWS][40];                 // K pad 19->32 (+bias col via tbl)
        } a;                                      // 9,600 (dead after xfr loads)
        struct {
            float sc[TB][N_PERM][N_PERM];         // 6,400
            float cs[TB][N_PERM];                 // 320
            bf16  y[16][DMP];                     // 4,096 (swizzled; rows TB..15 stale, masked)
        } p;                                      // 10,816
    } rA;
    __shared__ __align__(16) union {              // 20,480 B
        bf16 hall[MROWS][DMP];                    // one 128-col half of MLP1 out
        bf16 t[MROWS][DMP];                       // t = x@M + w' (after MLP2)
    } rB;
    __shared__ __align__(16) union {              // 20,480 B
        bf16 x[MROWS][DMP];                       // edge_feat (dead after y)
        bf16 hr[16][HID];                         // 8,192 (swizzled; rows TB..15 garbage)
    } rC;

    const f32x4 zf = {0.f, 0.f, 0.f, 0.f};

    // ---- stage 0: flat input vector + gather table -> LDS ----
    for (int i = tid; i < TB * 120; i += 256) {
        int bi = i / 120, c = i - bi * 120;
        float v = 0.f;
        if      (c < OBS_LEN) v = obs[(b0 + bi) * OBS_LEN + c];
        else if (c < 115)     v = g[(b0 + bi) * GOAL_DIM + (c - OBS_LEN)]
                                - ag[(b0 + bi) * GOAL_DIM + (c - OBS_LEN)];
        else if (c == 115)    v = 1.0f;
        rA.a.flat[bi][c] = v;
    }
    for (int i = tid; i < N_PERM * 32; i += 256)
        ((short*)rA.a.tbl)[i] = ((const short*)(wp + OFF_TBL))[i];
    __syncthreads();

    // ---- stage 1: build 80 x 32 edge inputs via gather table ----
    for (int idx = tid; idx < MROWS * 32; idx += 256) {
        int m = idx >> 5, c = idx & 31;
        int bi = m / N_PERM, p = m - bi * N_PERM;
        float v = rA.a.flat[bi][rA.a.tbl[p * 32 + c]];
        *(unsigned short*)&rA.a.inp[m][c] = bfr(v);
    }
    __syncthreads();

    // MLP1 input fragments (live across both phases)
    s16x8 xfr[5];
    #pragma unroll
    for (int mt = 0; mt < 5; ++mt)
        xfr[mt] = *(const s16x8*)(&rA.a.inp[mt * 16 + l15][lq * 8]);

    // MLP2 accumulators (live across both phases)
    f32x4 m2a[5], m2b[5];
    #pragma unroll
    for (int mt = 0; mt < 5; ++mt) { m2a[mt] = zf; m2b[mt] = zf; }
    const int nt0 = wav * 2, nt1 = nt0 + 1;

    // ---- two-phase MLP1 (19->256) + MLP2 (256->128), hall = 128-col half ----
    #pragma unroll
    for (int ph = 0; ph < 2; ++ph) {
        #pragma unroll
        for (int ntl = 0; ntl < 2; ++ntl) {
            int ntg = ph * 8 + wav * 2 + ntl;     // global nt 0..15
            s16x8 wfr = *(const s16x8*)(wp + OFF_W1 + ntg * 512 + (lq * 16 + l15) * 8);
            int nloc = (wav * 2 + ntl) * 16 + lq * 4;   // col within half
            #pragma unroll
            for (int mt = 0; mt < 5; ++mt) {
                f32x4 acc = MFMA16(wfr, xfr[mt], zf);
                store_c4(&rB.hall[0][0], mt * 16 + l15, DMP, nloc, 15, acc, zf, true);
            }
        }
        __syncthreads();
        #pragma unroll
        for (int ktl = 0; ktl < 4; ++ktl) {
            int ktg = ph * 4 + ktl;
            s16x8 wf0 = *(const s16x8*)(wp + OFF_W2 + (nt0 * 8 + ktg) * 512 + (lq * 16 + l15) * 8);
            s16x8 wf1 = *(const s16x8*)(wp + OFF_W2 + (nt1 * 8 + ktg) * 512 + (lq * 16 + l15) * 8);
            #pragma unroll
            for (int mt = 0; mt < 5; ++mt) {
                s16x8 a = frag_lds(&rB.hall[0][0], mt * 16 + l15, DMP, ktl * 32 + lq * 8, 15);
                m2a[mt] = MFMA16(wf0, a, m2a[mt]);
                m2b[mt] = MFMA16(wf1, a, m2b[mt]);
            }
        }
        // barrier only between ph0's hall reads and ph1's hall overwrite
        if (ph == 0) __syncthreads();
    }
    // MLP2 epilogue -> x
    {
        f32x4 bs0 = *(const f32x4*)(b2v + nt0 * 16 + lq * 4);
        f32x4 bs1 = *(const f32x4*)(b2v + nt1 * 16 + lq * 4);
        #pragma unroll
        for (int mt = 0; mt < 5; ++mt) {
            int m = mt * 16 + l15;
            store_c4(&rC.x[0][0], m, DMP, nt0 * 16 + lq * 4, 15, m2a[mt], bs0, true);
            store_c4(&rC.x[0][0], m, DMP, nt1 * 16 + lq * 4, 15, m2b[mt], bs1, true);
        }
    }
    __syncthreads();

    // ---- stage 4: t = x@M + w' (Q/K folded; 1/sqrt(128) inside M,w') ----
    {
        const float* wf = (const float*)(wp + OFF_WP);
        f32x4 a0[5], a1[5];
        #pragma unroll
        for (int mt = 0; mt < 5; ++mt) { a0[mt] = zf; a1[mt] = zf; }
        #pragma unroll
        for (int kt = 0; kt < 4; ++kt) {
            s16x8 wf0 = *(const s16x8*)(wp + OFF_M + (nt0 * 4 + kt) * 512 + (lq * 16 + l15) * 8);
            s16x8 wf1 = *(const s16x8*)(wp + OFF_M + (nt1 * 4 + kt) * 512 + (lq * 16 + l15) * 8);
            #pragma unroll
            for (int mt = 0; mt < 5; ++mt) {
                s16x8 a = frag_lds(&rC.x[0][0], mt * 16 + l15, DMP, kt * 32 + lq * 8, 15);
                a0[mt] = MFMA16(wf0, a, a0[mt]);
                a1[mt] = MFMA16(wf1, a, a1[mt]);
            }
        }
        f32x4 bs0 = *(const f32x4*)(wf + nt0 * 16 + lq * 4);
        f32x4 bs1 = *(const f32x4*)(wf + nt1 * 16 + lq * 4);
        #pragma unroll
        for (int mt = 0; mt < 5; ++mt) {
            int m = mt * 16 + l15;
            store_c4(&rB.t[0][0], m, DMP, nt0 * 16 + lq * 4, 15, a0[mt], bs0, false);
            store_c4(&rB.t[0][0], m, DMP, nt1 * 16 + lq * 4, 15, a1[mt], bs1, false);
        }
    }
    __syncthreads();

    // ---- stage 5: scores'[p][q] = t_p . x_q  (wave bi owns sc[bi]) ----
    {
        const int bi = wav;
        const int r0 = bi * N_PERM;
        f32x4 c00 = zf, c01 = zf, c10 = zf, c11 = zf;
        #pragma unroll
        for (int kt = 0; kt < 4; ++kt) {
            int kof = kt * 32 + lq * 8;
            s16x8 a0 = frag_lds(&rB.t[0][0], r0 + l15,      DMP, kof, 15);
            s16x8 a1 = frag_lds(&rB.t[0][0], r0 + 16 + l15, DMP, kof, 15);  // rows>79 garbage, masked
            s16x8 k0 = frag_lds(&rC.x[0][0], r0 + l15,      DMP, kof, 15);
            s16x8 k1 = frag_lds(&rC.x[0][0], r0 + 16 + l15, DMP, kof, 15);
            c00 = MFMA16(a0, k0, c00);  c01 = MFMA16(a0, k1, c01);
            c10 = MFMA16(a1, k0, c10);  c11 = MFMA16(a1, k1, c11);
        }
        #pragma unroll
        for (int r = 0; r < 4; ++r) {
            int pr = lq * 4 + r, qc = l15;
            rA.p.sc[bi][pr][qc] = c00[r];
            if (qc + 16 < N_PERM) rA.p.sc[bi][pr][qc + 16] = c01[r];
            if (pr + 16 < N_PERM) {
                rA.p.sc[bi][pr + 16][qc] = c10[r];
                if (qc + 16 < N_PERM) rA.p.sc[bi][pr + 16][qc + 16] = c11[r];
            }
        }
    }
    // no barrier: stages 5..7 wave-private per bi

    // ---- stage 6: row softmax (lane = row), then column sums ----
    if (lane < N_PERM) {
        float* scrow = rA.p.sc[wav][lane];
        float mx = -1e30f;
        #pragma unroll
        for (int qq = 0; qq < N_PERM; ++qq) mx = fmaxf(mx, scrow[qq]);
        float sum = 0.f;
        #pragma unroll
        for (int qq = 0; qq < N_PERM; ++qq) { float e = __expf(scrow[qq] - mx); scrow[qq] = e; sum += e; }
        float inv = 1.f / sum;
        #pragma unroll
        for (int qq = 0; qq < N_PERM; ++qq) scrow[qq] *= inv;
    }
    if (lane < N_PERM) {
        float cs = 0.f;
        #pragma unroll
        for (int p = 0; p < N_PERM; ++p) cs += rA.p.sc[wav][p][lane];
        rA.p.cs[wav][lane] = cs;
    }

    // ---- stage 7: y[bi] = sum_q cs[q] * x[bi*20+q]  (V-GEMM eliminated) ----
    {
        int bi = wav, j0 = lane * 2;
        float a0 = 0.f, a1 = 0.f;
        #pragma unroll
        for (int qq = 0; qq < N_PERM; ++qq) {
            int row  = bi * N_PERM + qq;
            int vcol = ((((j0 >> 3) ^ (row & 15)) << 3) | (j0 & 7));
            unsigned w = *(const unsigned*)(&rC.x[row][vcol]);
            float c = rA.p.cs[bi][qq];
            a0 += c * __uint_as_float(w << 16);
            a1 += c * __uint_as_float(w & 0xffff0000u);
        }
        int pcol = ((((j0 >> 3) ^ (bi & 15)) << 3) | (j0 & 7));
        *(unsigned*)(&rA.p.y[bi][pcol]) = pkbf(a0, a1);
    }
    __syncthreads();

    // ---- stage 8: hr = relu(y@Wvr + bvr)  (Wv,Wr composed) ----
    {
        s16x8 pfr[4];
        #pragma unroll
        for (int kt = 0; kt < 4; ++kt)
            pfr[kt] = frag_lds(&rA.p.y[0][0], l15, DMP, kt * 32 + lq * 8, 15);
        f32x4 acc[4];
        #pragma unroll
        for (int i = 0; i < 4; ++i) acc[i] = zf;
        #pragma unroll
        for (int kt = 0; kt < 4; ++kt)
            #pragma unroll
            for (int i = 0; i < 4; ++i) {
                int nt = wav * 4 + i;
                s16x8 wf = *(const s16x8*)(wp + OFF_WVR + (nt * 4 + kt) * 512 + (lq * 16 + l15) * 8);
                acc[i] = MFMA16(wf, pfr[kt], acc[i]);
            }
        const float* bvr = (const float*)(wp + OFF_BVR);
        #pragma unroll
        for (int i = 0; i < 4; ++i) {
            int n0 = (wav * 4 + i) * 16 + lq * 4;
            f32x4 bs = *(const f32x4*)(bvr + n0);
            store_c4(&rC.hr[0][0], l15, HID, n0, 15, acc[i], bs, true);
        }
    }
    __syncthreads();

    // ---- stage 9: heads via MFMA on wave 0: D^T = Wh^T . hr^T (K=256, 8 kt) ----
    if (wav == 0) {
        f32x4 acc = zf;
        #pragma unroll
        for (int kt = 0; kt < 8; ++kt) {
            s16x8 wh = *(const s16x8*)(wp + OFF_WH + kt * 512 + (lq * 16 + l15) * 8);
            s16x8 hf = frag_lds(&rC.hr[0][0], l15, HID, kt * 32 + lq * 8, 15);
            acc = MFMA16(wh, hf, acc);
        }
        // C layout: col = l15 = bi (valid <TB); row = lq*4+r = head output o (valid lq<2)
        if (l15 < TB && lq < 2) {
            int bi = l15;
            if (lq == 0) {
                #pragma unroll
                for (int r = 0; r < 4; ++r)
                    out[(b0 + bi) * ACT + r] = acc[r] + bm[r];
            } else {
                #pragma unroll
                for (int r = 0; r < 4; ++r) {
                    float v = acc[r] + bsv[r];
                    out[BATCH * ACT + (b0 + bi) * ACT + r] = fminf(fmaxf(v, -20.f), 2.f);
                }
            }
        }
    }
}

extern "C" void kernel_launch(void* const* d_in, const int* in_sizes, int n_in,
                              void* d_out, int out_size, void* d_ws, size_t ws_size,
                              hipStream_t stream) {
    (void)in_sizes; (void)n_in; (void)out_size; (void)ws_size;
    const float* obs = (const float*)d_in[0];
    const float* ag  = (const float*)d_in[1];
    const float* g   = (const float*)d_in[2];
    const float* W1  = (const float*)d_in[3];
    const float* b1  = (const float*)d_in[4];
    const float* W2  = (const float*)d_in[5];
    const float* b2  = (const float*)d_in[6];
    const float* Wq  = (const float*)d_in[7];
    const float* bq  = (const float*)d_in[8];
    const float* Wk  = (const float*)d_in[9];
    const float* Wv  = (const float*)d_in[11];
    const float* bv  = (const float*)d_in[12];
    const float* Wr  = (const float*)d_in[13];
    const float* br  = (const float*)d_in[14];
    const float* Wm  = (const float*)d_in[15];
    const float* bm  = (const float*)d_in[16];
    const float* Ws  = (const float*)d_in[17];
    const float* bs  = (const float*)d_in[18];
    const int*  edges    = (const int*)d_in[19];
    const int*  pred_ids = (const int*)d_in[20];
    float* out = (float*)d_out;
    bf16*  wp  = (bf16*)d_ws;

    prepack_kernel<<<(PACK_TOTAL + 255) / 256, 256, 0, stream>>>(
        W1, b1, W2, Wq, bq, Wk, Wv, bv, Wr, br, Wm, Ws, edges, pred_ids, wp);
    actor_main<<<BATCH / TB, 256, 0, stream>>>(
        obs, ag, g, b2, bm, bs, wp, out);
}